// Round 5
// baseline (186.061 us; speedup 1.0000x reference)
//
#include <hip/hip_runtime.h>
#include <hip/hip_bf16.h>

// MHA fwd: B=2, S=2048, D=1024, H=16, HD=64. fp32 in/out, bf16 MFMA internals.
// R15: attn double-buffered (T3-minimum recipe): KVBLK=64, K/V LDS x2 (41 KB,
// 3 blocks/CU). Per tile: STAGE(next)->compute(cur)->one __syncthreads().
// The implicit vmcnt(0) drain now lands AFTER ~350cyc of compute instead of
// naked between barriers; barriers per k-element halved.
// Swapped QK^T (R14): mfma(kf,qf) -> lane holds q-row l16, 4 contig k-cols;
// P-store = bf16x4 b64. GEMMs unchanged (R10 geometry).

typedef __bf16 bf16x8 __attribute__((ext_vector_type(8)));
typedef __bf16 bf16x4 __attribute__((ext_vector_type(4)));
typedef float f32x4 __attribute__((ext_vector_type(4)));

#define S_LEN 2048
#define DMODEL 1024
#define NHEAD 16
#define HDIM 64
#define MROWS 4096  // B*S

#define AS1 __attribute__((address_space(1)))
#define AS3 __attribute__((address_space(3)))

#define QSCALE 0.18033688f  // 0.125 * log2e: scores come out in log2 units
#define LDP4 72             // Ps row pitch (bf16): 144 B = 9x16B

// ---------------- cast x (fp32 -> bf16), 4 elems/thread ----------------
__global__ void cast_x_kernel(const float* __restrict__ X, __bf16* __restrict__ Xb) {
    int i = (blockIdx.x * blockDim.x + threadIdx.x) * 4;
    float4 f = *(const float4*)&X[i];
    Xb[i + 0] = (__bf16)f.x;
    Xb[i + 1] = (__bf16)f.y;
    Xb[i + 2] = (__bf16)f.z;
    Xb[i + 3] = (__bf16)f.w;
}

// ------------- transpose + cast all 4 weights: WT[n][k] = W[k][n] -------------
__global__ void transpose_cast_kernel(
    const float* __restrict__ W0, const float* __restrict__ W1,
    const float* __restrict__ W2, const float* __restrict__ W3,
    __bf16* __restrict__ T0, __bf16* __restrict__ T1,
    __bf16* __restrict__ T2, __bf16* __restrict__ T3) {
    const float* W = (blockIdx.z == 0) ? W0 : (blockIdx.z == 1) ? W1 : (blockIdx.z == 2) ? W2 : W3;
    __bf16* WT = (blockIdx.z == 0) ? T0 : (blockIdx.z == 1) ? T1 : (blockIdx.z == 2) ? T2 : T3;
    __shared__ float tile[32][33];
    int bx = blockIdx.x, by = blockIdx.y;
    int tx = threadIdx.x;
    for (int i = threadIdx.y; i < 32; i += 8)
        tile[i][tx] = W[(size_t)(by * 32 + i) * DMODEL + bx * 32 + tx];
    __syncthreads();
    for (int i = threadIdx.y; i < 32; i += 8)
        WT[(size_t)(bx * 32 + i) * DMODEL + by * 32 + tx] = (__bf16)tile[tx][i];
}

// ------------- GEMM QKV: 128x64 tile, BK=64, glds(16B) + XOR swizzle ---------
__global__ __launch_bounds__(256) void gemm_qkv_kernel(
    const __bf16* __restrict__ X,
    const __bf16* __restrict__ WqT, const __bf16* __restrict__ WkT, const __bf16* __restrict__ WvT,
    const float* __restrict__ bq, const float* __restrict__ bk, const float* __restrict__ bv,
    __bf16* __restrict__ Q, __bf16* __restrict__ K, __bf16* __restrict__ Vt) {
    const int which = blockIdx.z;
    const __bf16* Bt = (which == 0) ? WqT : (which == 1) ? WkT : WvT;
    const float* bias = (which == 0) ? bq : (which == 1) ? bk : bv;
    __bf16* Out = (which == 0) ? Q : (which == 1) ? K : Vt;

    __shared__ alignas(16) __bf16 As[128 * 64];
    __shared__ alignas(16) __bf16 Bs[64 * 64];

    const int tid = threadIdx.x;
    const int lane = tid & 63;
    const int wave = tid >> 6;
    const int wm = wave >> 1, wn = wave & 1;
    const int quad = lane >> 4;
    const int l16 = lane & 15;
    const int m0 = blockIdx.x * 128;   // m-tile on x (XCD locality)
    const int n0 = blockIdx.y * 64;
    const int r8 = lane >> 3;
    const int sc8 = ((lane & 7) ^ r8) * 8;
    const int gq0 = ((0 + quad) ^ (l16 & 7)) * 8;
    const int gq1 = ((4 + quad) ^ (l16 & 7)) * 8;

    f32x4 acc[4][2] = {};

    for (int k0 = 0; k0 < DMODEL; k0 += 64) {
        __syncthreads();
#pragma unroll
        for (int p = 0; p < 4; p++) {  // A: 128 rows
            const int row = wave * 32 + p * 8;
            __builtin_amdgcn_global_load_lds(
                (const AS1 void*)&X[(size_t)(m0 + row + r8) * DMODEL + k0 + sc8],
                (AS3 void*)&As[row * 64], 16, 0, 0);
        }
#pragma unroll
        for (int p = 0; p < 2; p++) {  // B: 64 rows
            const int row = wave * 16 + p * 8;
            __builtin_amdgcn_global_load_lds(
                (const AS1 void*)&Bt[(size_t)(n0 + row + r8) * DMODEL + k0 + sc8],
                (AS3 void*)&Bs[row * 64], 16, 0, 0);
        }
        __syncthreads();
#pragma unroll
        for (int ks = 0; ks < 2; ks++) {
            const int g = ks ? gq1 : gq0;
            bf16x8 af[4], bfr[2];
#pragma unroll
            for (int t = 0; t < 4; t++)
                af[t] = *(bf16x8*)&As[(wm * 64 + t * 16 + l16) * 64 + g];
#pragma unroll
            for (int t = 0; t < 2; t++)
                bfr[t] = *(bf16x8*)&Bs[(wn * 32 + t * 16 + l16) * 64 + g];
#pragma unroll
            for (int mt = 0; mt < 4; mt++)
#pragma unroll
                for (int nt = 0; nt < 2; nt++)
                    acc[mt][nt] = __builtin_amdgcn_mfma_f32_16x16x32_bf16(af[mt], bfr[nt], acc[mt][nt], 0, 0, 0);
        }
    }

    // C/D layout: col = lane&15, row = quad*4 + reg  [m89-verified]
#pragma unroll
    for (int mt = 0; mt < 4; mt++)
#pragma unroll
        for (int nt = 0; nt < 2; nt++) {
            const int n = n0 + wn * 32 + nt * 16 + l16;
            const float bn = bias[n];
            const int h = n >> 6, hd = n & 63;
            const int mbase = m0 + wm * 64 + mt * 16 + quad * 4;
            if (which == 2) {
                __bf16 pk[4];
#pragma unroll
                for (int r = 0; r < 4; r++) pk[r] = (__bf16)(acc[mt][nt][r] + bn);
                const int m = mbase;
                const int b = m >> 11, s = m & 2047;
                *(uint2*)&Out[(((size_t)(b * NHEAD + h) * HDIM + hd) * S_LEN) + s] = *(uint2*)pk;
            } else {
                const float sc = (which == 0) ? QSCALE : 1.0f;  // Q: fold 1/8 * log2e
#pragma unroll
                for (int r = 0; r < 4; r++) {
                    const int m = mbase + r;
                    const int b = m >> 11, s = m & 2047;
                    Out[(((size_t)(b * NHEAD + h) * S_LEN + s) * HDIM) + hd] =
                        (__bf16)((acc[mt][nt][r] + bn) * sc);
                }
            }
        }
}

// ------------- GEMM OUT: 64x64 tile, BK=64, grid (64,16): m-tile on x --------
__global__ __launch_bounds__(256) void gemm_out_kernel(
    const __bf16* __restrict__ A, const __bf16* __restrict__ Bt,
    const float* __restrict__ bias, float* __restrict__ Y) {
    __shared__ alignas(16) __bf16 As[64 * 64];
    __shared__ alignas(16) __bf16 Bs[64 * 64];

    const int tid = threadIdx.x;
    const int lane = tid & 63;
    const int wave = tid >> 6;
    const int wm = wave >> 1, wn = wave & 1;
    const int quad = lane >> 4;
    const int l16 = lane & 15;
    const int m0 = blockIdx.x * 64;    // m-tile on x (XCD locality)
    const int n0 = blockIdx.y * 64;
    const int r8 = lane >> 3;
    const int sc8 = ((lane & 7) ^ r8) * 8;
    const int gq0 = ((0 + quad) ^ (l16 & 7)) * 8;
    const int gq1 = ((4 + quad) ^ (l16 & 7)) * 8;

    f32x4 acc[2][2] = {};

    for (int k0 = 0; k0 < DMODEL; k0 += 64) {
        __syncthreads();
#pragma unroll
        for (int p = 0; p < 2; p++) {
            const int row = wave * 16 + p * 8;
            __builtin_amdgcn_global_load_lds(
                (const AS1 void*)&A[(size_t)(m0 + row + r8) * DMODEL + k0 + sc8],
                (AS3 void*)&As[row * 64], 16, 0, 0);
            __builtin_amdgcn_global_load_lds(
                (const AS1 void*)&Bt[(size_t)(n0 + row + r8) * DMODEL + k0 + sc8],
                (AS3 void*)&Bs[row * 64], 16, 0, 0);
        }
        __syncthreads();
#pragma unroll
        for (int ks = 0; ks < 2; ks++) {
            const int g = ks ? gq1 : gq0;
            bf16x8 af[2], bfr[2];
#pragma unroll
            for (int t = 0; t < 2; t++) {
                af[t]  = *(bf16x8*)&As[(wm * 32 + t * 16 + l16) * 64 + g];
                bfr[t] = *(bf16x8*)&Bs[(wn * 32 + t * 16 + l16) * 64 + g];
            }
#pragma unroll
            for (int mt = 0; mt < 2; mt++)
#pragma unroll
                for (int nt = 0; nt < 2; nt++)
                    acc[mt][nt] = __builtin_amdgcn_mfma_f32_16x16x32_bf16(af[mt], bfr[nt], acc[mt][nt], 0, 0, 0);
        }
    }

#pragma unroll
    for (int mt = 0; mt < 2; mt++)
#pragma unroll
        for (int nt = 0; nt < 2; nt++)
#pragma unroll
            for (int r = 0; r < 4; r++) {
                int m = m0 + wm * 32 + mt * 16 + quad * 4 + r;
                int n = n0 + wn * 32 + nt * 16 + l16;
                Y[(size_t)m * DMODEL + n] = acc[mt][nt][r] + bias[n];
            }
}

// -------- flash attention (R15: KVBLK=64 double-buffered, swapped QK^T) ------
// Ks[2][64 k-rows][64 hd], Vs[2][64 hd][64 k-cols] (both pitch 64, XOR-swz
// chunk ^ (row&7)), Ps[4][16 q][72 pitch]. Per tile: 8 QK + 8 PV + 2 ones
// MFMA per wave. Stage of tile kb+1 issued BEFORE compute of tile kb; single
// __syncthreads per tile (drain overlapped by compute).

template <bool MASK>
__device__ __forceinline__ void attn_tile64(
    const __bf16* Ks, const __bf16* Vs, __bf16* Psw,
    const bf16x8& qf0, const bf16x8& qf1, const bf16x8& onef,
    f32x4 (&oacc)[4], f32x4& lacc,
    int qg, int k0, int quad, int l16, int g0, int g1) {
    f32x4 sacc[4];
#pragma unroll
    for (int nt = 0; nt < 4; nt++) sacc[nt] = (f32x4){0.f, 0.f, 0.f, 0.f};
#pragma unroll
    for (int nt = 0; nt < 4; nt++) {
        const int krow = (nt * 16 + l16) * 64;
        bf16x8 kf0 = *(bf16x8*)&Ks[krow + g0];
        bf16x8 kf1 = *(bf16x8*)&Ks[krow + g1];
        // swapped: A=K rows, B=Q rows -> D = S^T (lane: q-row l16, k quad*4+r)
        sacc[nt] = __builtin_amdgcn_mfma_f32_16x16x32_bf16(kf0, qf0, sacc[nt], 0, 0, 0);
        sacc[nt] = __builtin_amdgcn_mfma_f32_16x16x32_bf16(kf1, qf1, sacc[nt], 0, 0, 0);
    }
#pragma unroll
    for (int nt = 0; nt < 4; nt++) {
        bf16x4 pv;
#pragma unroll
        for (int r = 0; r < 4; r++) {
            if (MASK) {
                const int kcol = k0 + nt * 16 + quad * 4 + r;
                pv[r] = (__bf16)((kcol > qg) ? 0.0f : __builtin_amdgcn_exp2f(sacc[nt][r]));
            } else {
                pv[r] = (__bf16)__builtin_amdgcn_exp2f(sacc[nt][r]);
            }
        }
        *(bf16x4*)&Psw[l16 * LDP4 + nt * 16 + quad * 4] = pv;
    }
#pragma unroll
    for (int ks = 0; ks < 2; ks++) {
        bf16x8 pf = *(bf16x8*)&Psw[l16 * LDP4 + ks * 32 + quad * 8];
        const int vg = (((ks * 4 + quad) ^ (l16 & 7)) * 8);
#pragma unroll
        for (int nt2 = 0; nt2 < 4; nt2++) {
            bf16x8 vf = *(bf16x8*)&Vs[(nt2 * 16 + l16) * 64 + vg];
            oacc[nt2] = __builtin_amdgcn_mfma_f32_16x16x32_bf16(pf, vf, oacc[nt2], 0, 0, 0);
        }
        lacc = __builtin_amdgcn_mfma_f32_16x16x32_bf16(pf, onef, lacc, 0, 0, 0);
    }
}

__global__ __launch_bounds__(256, 3) void attn_kernel(
    const __bf16* __restrict__ Q, const __bf16* __restrict__ K, const __bf16* __restrict__ Vt,
    __bf16* __restrict__ Aout) {
    const int id = blockIdx.x;
    const int bh = id & 31;                 // XCD-pinned: id%8 == bh%8
    const int qt = 31 - (id >> 5);          // big tiles first
    const int b = bh >> 4, h = bh & 15;
    const int tid = threadIdx.x, lane = tid & 63, wave = tid >> 6;
    const int quad = lane >> 4, l16 = lane & 15;

    __shared__ alignas(16) __bf16 Ks[2][64 * 64];
    __shared__ alignas(16) __bf16 Vs[2][64 * 64];
    __shared__ alignas(16) __bf16 Ps[4][16 * LDP4];

    const size_t base = (size_t)bh * S_LEN * HDIM;   // same for K and Vt
    const int q0 = qt * 64;
    const int qrow = q0 + wave * 16 + l16;

    bf16x8 qf0 = *(const bf16x8*)&Q[base + (size_t)qrow * HDIM + quad * 8];
    bf16x8 qf1 = *(const bf16x8*)&Q[base + (size_t)qrow * HDIM + 32 + quad * 8];

    bf16x8 onef;
#pragma unroll
    for (int jj = 0; jj < 8; jj++) onef[jj] = (__bf16)1.0f;

    f32x4 oacc[4] = {};
    f32x4 lacc = {};
    __bf16* Psw = &Ps[wave][0];

    // staging lane roles (8 rows per glds, XOR chunk swizzle; K and V identical
    // in form since both LDS tiles are pitch-64 = 128 B rows)
    const int r8k = lane >> 3;
    const int sck = ((lane & 7) ^ r8k) * 8;
    // fragment-read granules (pitch 64)
    const int g0 = (quad ^ (l16 & 7)) * 8;
    const int g1 = g0 ^ 32;
    const int qg = q0 + wave * 16 + l16;   // this lane's q-row (swapped layout)

    const int kb_all = qt + 1;

    // prologue: stage tile 0 into buffer 0
#pragma unroll
    for (int p = 0; p < 2; p++) {
        const int row = wave * 16 + p * 8;
        __builtin_amdgcn_global_load_lds(
            (const AS1 void*)&K[base + (size_t)(row + r8k) * HDIM + sck],
            (AS3 void*)&Ks[0][row * 64], 16, 0, 0);
        __builtin_amdgcn_global_load_lds(
            (const AS1 void*)&Vt[base + (size_t)(row + r8k) * S_LEN + sck],
            (AS3 void*)&Vs[0][row * 64], 16, 0, 0);
    }
    __syncthreads();

    int cur = 0;
    for (int kb = 0; kb < kb_all; kb++) {
        // issue next tile's stage first; latency hides under compute below
        if (kb + 1 < kb_all) {
            const int k1 = (kb + 1) * 64;
            const int nxt = cur ^ 1;
#pragma unroll
            for (int p = 0; p < 2; p++) {
                const int row = wave * 16 + p * 8;
                __builtin_amdgcn_global_load_lds(
                    (const AS1 void*)&K[base + (size_t)(k1 + row + r8k) * HDIM + sck],
                    (AS3 void*)&Ks[nxt][row * 64], 16, 0, 0);
                __builtin_amdgcn_global_load_lds(
                    (const AS1 void*)&Vt[base + (size_t)(row + r8k) * S_LEN + k1 + sck],
                    (AS3 void*)&Vs[nxt][row * 64], 16, 0, 0);
            }
        }

        const int k0 = kb * 64;
        if (kb == kb_all - 1)
            attn_tile64<true>(Ks[cur], Vs[cur], Psw, qf0, qf1, onef, oacc, lacc,
                              qg, k0, quad, l16, g0, g1);
        else
            attn_tile64<false>(Ks[cur], Vs[cur], Psw, qf0, qf1, onef, oacc, lacc,
                               qg, k0, quad, l16, g0, g1);
        __syncthreads();   // drains next-tile stage (overlapped) + read fence
        cur ^= 1;
    }

    float rl[4];
#pragma unroll
    for (int r = 0; r < 4; r++) rl[r] = 1.0f / lacc[r];
#pragma unroll
    for (int nt2 = 0; nt2 < 4; nt2++)
#pragma unroll
        for (int r = 0; r < 4; r++) {
            int qq = q0 + wave * 16 + quad * 4 + r;
            int col = h * HDIM + nt2 * 16 + l16;
            Aout[(size_t)(b * S_LEN + qq) * DMODEL + col] = (__bf16)(oacc[nt2][r] * rl[r]);
        }
}

extern "C" void kernel_launch(void* const* d_in, const int* in_sizes, int n_in,
                              void* d_out, int out_size, void* d_ws, size_t ws_size,
                              hipStream_t stream) {
    const float* x  = (const float*)d_in[0];
    // d_in[1] = mask: causal triu, reproduced analytically
    const float* wq = (const float*)d_in[2];
    const float* bq = (const float*)d_in[3];
    const float* wk = (const float*)d_in[4];
    const float* bk = (const float*)d_in[5];
    const float* wv = (const float*)d_in[6];
    const float* bv = (const float*)d_in[7];
    const float* wo = (const float*)d_in[8];
    const float* bo = (const float*)d_in[9];
    float* out = (float*)d_out;

    char* ws = (char*)d_ws;
    __bf16* xb  = (__bf16*)(ws);                          // 8 MiB
    __bf16* wqT = (__bf16*)(ws + ((size_t)8  << 20));     // 2 MiB each
    __bf16* wkT = (__bf16*)(ws + ((size_t)10 << 20));
    __bf16* wvT = (__bf16*)(ws + ((size_t)12 << 20));
    __bf16* woT = (__bf16*)(ws + ((size_t)14 << 20));
    __bf16* Qb  = (__bf16*)(ws + ((size_t)16 << 20));     // 8 MiB each
    __bf16* Kb  = (__bf16*)(ws + ((size_t)24 << 20));
    __bf16* Vtb = (__bf16*)(ws + ((size_t)32 << 20));     // V^T [B,H,HD,S]
    __bf16* Ab  = (__bf16*)(ws + ((size_t)40 << 20));     // 8 MiB

    cast_x_kernel<<<4096, 256, 0, stream>>>(x, xb);
    transpose_cast_kernel<<<dim3(32, 32, 4), dim3(32, 8), 0, stream>>>(
        wq, wk, wv, wo, wqT, wkT, wvT, woT);
    gemm_qkv_kernel<<<dim3(32, 16, 3), 256, 0, stream>>>(xb, wqT, wkT, wvT, bq, bk, bv, Qb, Kb, Vtb);
    attn_kernel<<<1024, 256, 0, stream>>>(Qb, Kb, Vtb, Ab);
    gemm_out_kernel<<<dim3(64, 16), 256, 0, stream>>>(Ab, woT, bo, out);
}

// Round 8
// 183.582 us; speedup vs baseline: 1.0135x; 1.0135x over previous
//
#include <hip/hip_runtime.h>
#include <hip/hip_bf16.h>

// MHA fwd: B=2, S=2048, D=1024, H=16, HD=64. fp32 in/out, bf16 MFMA internals.
// R17 = R16 + one-line correctness fix: PV V-read now offsets chunks by the
// wave's k-half (kl0>>3). R16 bug: wk=1 waves read V cols 0..63 for P rows
// 64..127 (audit found K-side had the kl0 offset, V-side didn't).
// R16 design: attn on 32x32x16 MFMA (half the LDS operand bytes/FLOP; attn is
// LDS-BW-bound). Swapped QK^T -> P^T in regs; PV A-frags assembled in-register
// via bf16-pack + shfl_xor(32); Ps LDS eliminated; l via ones-MFMA.
// GEMMs: R10 geometry (qkv 128x64 @ (32,16,3), out 64x64 @ (64,16)).
// R18: identical resubmit — R7 bench was an infra failure (container), R17's
// correctness fix has not yet been measured.

typedef __bf16 bf16x8 __attribute__((ext_vector_type(8)));
typedef __bf16 bf16x4 __attribute__((ext_vector_type(4)));
typedef __bf16 bf16x2 __attribute__((ext_vector_type(2)));
typedef float f32x4 __attribute__((ext_vector_type(4)));
typedef float f32x16 __attribute__((ext_vector_type(16)));
typedef unsigned int u32x4 __attribute__((ext_vector_type(4)));

#define S_LEN 2048
#define DMODEL 1024
#define NHEAD 16
#define HDIM 64
#define MROWS 4096  // B*S

#define AS1 __attribute__((address_space(1)))
#define AS3 __attribute__((address_space(3)))

#define QSCALE 0.18033688f  // 0.125 * log2e: scores come out in log2 units

// ---------------- cast x (fp32 -> bf16), 4 elems/thread ----------------
__global__ void cast_x_kernel(const float* __restrict__ X, __bf16* __restrict__ Xb) {
    int i = (blockIdx.x * blockDim.x + threadIdx.x) * 4;
    float4 f = *(const float4*)&X[i];
    Xb[i + 0] = (__bf16)f.x;
    Xb[i + 1] = (__bf16)f.y;
    Xb[i + 2] = (__bf16)f.z;
    Xb[i + 3] = (__bf16)f.w;
}

// ------------- transpose + cast all 4 weights: WT[n][k] = W[k][n] -------------
__global__ void transpose_cast_kernel(
    const float* __restrict__ W0, const float* __restrict__ W1,
    const float* __restrict__ W2, const float* __restrict__ W3,
    __bf16* __restrict__ T0, __bf16* __restrict__ T1,
    __bf16* __restrict__ T2, __bf16* __restrict__ T3) {
    const float* W = (blockIdx.z == 0) ? W0 : (blockIdx.z == 1) ? W1 : (blockIdx.z == 2) ? W2 : W3;
    __bf16* WT = (blockIdx.z == 0) ? T0 : (blockIdx.z == 1) ? T1 : (blockIdx.z == 2) ? T2 : T3;
    __shared__ float tile[32][33];
    int bx = blockIdx.x, by = blockIdx.y;
    int tx = threadIdx.x;
    for (int i = threadIdx.y; i < 32; i += 8)
        tile[i][tx] = W[(size_t)(by * 32 + i) * DMODEL + bx * 32 + tx];
    __syncthreads();
    for (int i = threadIdx.y; i < 32; i += 8)
        WT[(size_t)(bx * 32 + i) * DMODEL + by * 32 + tx] = (__bf16)tile[tx][i];
}

// ------------- GEMM QKV: 128x64 tile, BK=64, glds(16B) + XOR swizzle ---------
__global__ __launch_bounds__(256) void gemm_qkv_kernel(
    const __bf16* __restrict__ X,
    const __bf16* __restrict__ WqT, const __bf16* __restrict__ WkT, const __bf16* __restrict__ WvT,
    const float* __restrict__ bq, const float* __restrict__ bk, const float* __restrict__ bv,
    __bf16* __restrict__ Q, __bf16* __restrict__ K, __bf16* __restrict__ Vt) {
    const int which = blockIdx.z;
    const __bf16* Bt = (which == 0) ? WqT : (which == 1) ? WkT : WvT;
    const float* bias = (which == 0) ? bq : (which == 1) ? bk : bv;
    __bf16* Out = (which == 0) ? Q : (which == 1) ? K : Vt;

    __shared__ alignas(16) __bf16 As[128 * 64];
    __shared__ alignas(16) __bf16 Bs[64 * 64];

    const int tid = threadIdx.x;
    const int lane = tid & 63;
    const int wave = tid >> 6;
    const int wm = wave >> 1, wn = wave & 1;
    const int quad = lane >> 4;
    const int l16 = lane & 15;
    const int m0 = blockIdx.x * 128;   // m-tile on x (XCD locality)
    const int n0 = blockIdx.y * 64;
    const int r8 = lane >> 3;
    const int sc8 = ((lane & 7) ^ r8) * 8;
    const int gq0 = ((0 + quad) ^ (l16 & 7)) * 8;
    const int gq1 = ((4 + quad) ^ (l16 & 7)) * 8;

    f32x4 acc[4][2] = {};

    for (int k0 = 0; k0 < DMODEL; k0 += 64) {
        __syncthreads();
#pragma unroll
        for (int p = 0; p < 4; p++) {  // A: 128 rows
            const int row = wave * 32 + p * 8;
            __builtin_amdgcn_global_load_lds(
                (const AS1 void*)&X[(size_t)(m0 + row + r8) * DMODEL + k0 + sc8],
                (AS3 void*)&As[row * 64], 16, 0, 0);
        }
#pragma unroll
        for (int p = 0; p < 2; p++) {  // B: 64 rows
            const int row = wave * 16 + p * 8;
            __builtin_amdgcn_global_load_lds(
                (const AS1 void*)&Bt[(size_t)(n0 + row + r8) * DMODEL + k0 + sc8],
                (AS3 void*)&Bs[row * 64], 16, 0, 0);
        }
        __syncthreads();
#pragma unroll
        for (int ks = 0; ks < 2; ks++) {
            const int g = ks ? gq1 : gq0;
            bf16x8 af[4], bfr[2];
#pragma unroll
            for (int t = 0; t < 4; t++)
                af[t] = *(bf16x8*)&As[(wm * 64 + t * 16 + l16) * 64 + g];
#pragma unroll
            for (int t = 0; t < 2; t++)
                bfr[t] = *(bf16x8*)&Bs[(wn * 32 + t * 16 + l16) * 64 + g];
#pragma unroll
            for (int mt = 0; mt < 4; mt++)
#pragma unroll
                for (int nt = 0; nt < 2; nt++)
                    acc[mt][nt] = __builtin_amdgcn_mfma_f32_16x16x32_bf16(af[mt], bfr[nt], acc[mt][nt], 0, 0, 0);
        }
    }

    // C/D layout: col = lane&15, row = quad*4 + reg  [m89-verified]
#pragma unroll
    for (int mt = 0; mt < 4; mt++)
#pragma unroll
        for (int nt = 0; nt < 2; nt++) {
            const int n = n0 + wn * 32 + nt * 16 + l16;
            const float bn = bias[n];
            const int h = n >> 6, hd = n & 63;
            const int mbase = m0 + wm * 64 + mt * 16 + quad * 4;
            if (which == 2) {
                __bf16 pk[4];
#pragma unroll
                for (int r = 0; r < 4; r++) pk[r] = (__bf16)(acc[mt][nt][r] + bn);
                const int m = mbase;
                const int b = m >> 11, s = m & 2047;
                *(uint2*)&Out[(((size_t)(b * NHEAD + h) * HDIM + hd) * S_LEN) + s] = *(uint2*)pk;
            } else {
                const float sc = (which == 0) ? QSCALE : 1.0f;  // Q: fold 1/8 * log2e
#pragma unroll
                for (int r = 0; r < 4; r++) {
                    const int m = mbase + r;
                    const int b = m >> 11, s = m & 2047;
                    Out[(((size_t)(b * NHEAD + h) * S_LEN + s) * HDIM) + hd] =
                        (__bf16)((acc[mt][nt][r] + bn) * sc);
                }
            }
        }
}

// ------------- GEMM OUT: 64x64 tile, BK=64, grid (64,16): m-tile on x --------
__global__ __launch_bounds__(256) void gemm_out_kernel(
    const __bf16* __restrict__ A, const __bf16* __restrict__ Bt,
    const float* __restrict__ bias, float* __restrict__ Y) {
    __shared__ alignas(16) __bf16 As[64 * 64];
    __shared__ alignas(16) __bf16 Bs[64 * 64];

    const int tid = threadIdx.x;
    const int lane = tid & 63;
    const int wave = tid >> 6;
    const int wm = wave >> 1, wn = wave & 1;
    const int quad = lane >> 4;
    const int l16 = lane & 15;
    const int m0 = blockIdx.x * 64;    // m-tile on x (XCD locality)
    const int n0 = blockIdx.y * 64;
    const int r8 = lane >> 3;
    const int sc8 = ((lane & 7) ^ r8) * 8;
    const int gq0 = ((0 + quad) ^ (l16 & 7)) * 8;
    const int gq1 = ((4 + quad) ^ (l16 & 7)) * 8;

    f32x4 acc[2][2] = {};

    for (int k0 = 0; k0 < DMODEL; k0 += 64) {
        __syncthreads();
#pragma unroll
        for (int p = 0; p < 2; p++) {
            const int row = wave * 16 + p * 8;
            __builtin_amdgcn_global_load_lds(
                (const AS1 void*)&A[(size_t)(m0 + row + r8) * DMODEL + k0 + sc8],
                (AS3 void*)&As[row * 64], 16, 0, 0);
            __builtin_amdgcn_global_load_lds(
                (const AS1 void*)&Bt[(size_t)(n0 + row + r8) * DMODEL + k0 + sc8],
                (AS3 void*)&Bs[row * 64], 16, 0, 0);
        }
        __syncthreads();
#pragma unroll
        for (int ks = 0; ks < 2; ks++) {
            const int g = ks ? gq1 : gq0;
            bf16x8 af[2], bfr[2];
#pragma unroll
            for (int t = 0; t < 2; t++) {
                af[t]  = *(bf16x8*)&As[(wm * 32 + t * 16 + l16) * 64 + g];
                bfr[t] = *(bf16x8*)&Bs[(wn * 32 + t * 16 + l16) * 64 + g];
            }
#pragma unroll
            for (int mt = 0; mt < 2; mt++)
#pragma unroll
                for (int nt = 0; nt < 2; nt++)
                    acc[mt][nt] = __builtin_amdgcn_mfma_f32_16x16x32_bf16(af[mt], bfr[nt], acc[mt][nt], 0, 0, 0);
        }
    }

#pragma unroll
    for (int mt = 0; mt < 2; mt++)
#pragma unroll
        for (int nt = 0; nt < 2; nt++)
#pragma unroll
            for (int r = 0; r < 4; r++) {
                int m = m0 + wm * 32 + mt * 16 + quad * 4 + r;
                int n = n0 + wn * 32 + nt * 16 + l16;
                Y[(size_t)m * DMODEL + n] = acc[mt][nt][r] + bias[n];
            }
}

// -------- flash attention (R17: 32x32x16 MFMA, in-register P) ----------------
// Ks[128 k][64 hd] (chunk ^= row&7), Vs[64 hd][128 k] (chunk ^= hd&15).
// Wave (wq,wk): 32 q-rows x 64 k-cols. Swapped QK: sacc = mfma(K,Q) = S^T,
// lane = q-col (lane&31), 16 k-rows via (r&3)+8*(r>>2)+4*(lane>>5).
// PA frags (P[q=lane&31][8 contig k]) assembled via bf16-pack + shfl_xor(32).
// O += mfma(PA, V); l += mfma(PA, ones) — lacc row layout == oacc row layout.
// V chunks offset by the wave's k-half (kl0>>3) — the R16 bug.
// Epilogue: k-half partial O/l reduced via LDS scratch (stride 49 f32).

static __device__ __forceinline__ unsigned pkbf2(float a, float b) {
    bf16x2 t;
    t[0] = (__bf16)a;
    t[1] = (__bf16)b;
    return __builtin_bit_cast(unsigned, t);
}

template <bool MASK>
__device__ __forceinline__ void attn_tile32(
    const __bf16* Ks, const __bf16* Vs,
    const bf16x8 (&qf)[4], const bf16x8& onesf,
    f32x16 (&oacc)[2], f32x16& lacc,
    int q_lane, int kl0, int kabs0, int lane) {
    const int l32 = lane & 31, hi = lane >> 5, l7 = lane & 7, l15 = lane & 15;
    const int cbase = kl0 >> 3;   // wave's V chunk base (0 or 8)
    bf16x8 pa[4];
#pragma unroll
    for (int sub = 0; sub < 2; sub++) {
        f32x16 s = {};
        const int row = kl0 + sub * 32 + l32;
#pragma unroll
        for (int j = 0; j < 4; j++) {
            const int ch = ((2 * j + hi) ^ l7) * 8;
            bf16x8 kf = *(const bf16x8*)&Ks[row * 64 + ch];
            s = __builtin_amdgcn_mfma_f32_32x32x16_bf16(kf, qf[j], s, 0, 0, 0);
        }
        float p[16];
#pragma unroll
        for (int r = 0; r < 16; r++) {
            const float e = __builtin_amdgcn_exp2f(s[r]);
            if (MASK) {
                const int kabs = kabs0 + sub * 32 + (r & 3) + 8 * (r >> 2) + 4 * hi;
                p[r] = (kabs > q_lane) ? 0.0f : e;
            } else {
                p[r] = e;
            }
        }
        const unsigned c0 = pkbf2(p[0], p[1]),   c1 = pkbf2(p[2], p[3]);
        const unsigned c2 = pkbf2(p[4], p[5]),   c3 = pkbf2(p[6], p[7]);
        const unsigned c4 = pkbf2(p[8], p[9]),   c5 = pkbf2(p[10], p[11]);
        const unsigned c6 = pkbf2(p[12], p[13]), c7 = pkbf2(p[14], p[15]);
        const unsigned sA0 = hi ? c0 : c2, sA1 = hi ? c1 : c3;
        const unsigned rA0 = __shfl_xor(sA0, 32, 64), rA1 = __shfl_xor(sA1, 32, 64);
        const unsigned sB0 = hi ? c4 : c6, sB1 = hi ? c5 : c7;
        const unsigned rB0 = __shfl_xor(sB0, 32, 64), rB1 = __shfl_xor(sB1, 32, 64);
        u32x4 wA, wB;
        if (hi) {
            wA[0] = rA0; wA[1] = rA1; wA[2] = c2; wA[3] = c3;
            wB[0] = rB0; wB[1] = rB1; wB[2] = c6; wB[3] = c7;
        } else {
            wA[0] = c0; wA[1] = c1; wA[2] = rA0; wA[3] = rA1;
            wB[0] = c4; wB[1] = c5; wB[2] = rB0; wB[3] = rB1;
        }
        pa[sub * 2]     = __builtin_bit_cast(bf16x8, wA);
        pa[sub * 2 + 1] = __builtin_bit_cast(bf16x8, wB);
    }
#pragma unroll
    for (int kblk = 0; kblk < 4; kblk++) {
#pragma unroll
        for (int dsub = 0; dsub < 2; dsub++) {
            const int hd = dsub * 32 + l32;
            const int ch = ((cbase + kblk * 2 + hi) ^ l15) * 8;   // R17 fix: +cbase
            bf16x8 vf = *(const bf16x8*)&Vs[hd * 128 + ch];
            oacc[dsub] = __builtin_amdgcn_mfma_f32_32x32x16_bf16(pa[kblk], vf, oacc[dsub], 0, 0, 0);
        }
        lacc = __builtin_amdgcn_mfma_f32_32x32x16_bf16(pa[kblk], onesf, lacc, 0, 0, 0);
    }
}

__global__ __launch_bounds__(256, 3) void attn_kernel(
    const __bf16* __restrict__ Q, const __bf16* __restrict__ K, const __bf16* __restrict__ Vt,
    __bf16* __restrict__ Aout) {
    const int id = blockIdx.x;
    const int bh = id & 31;                 // XCD-pinned: id%8 == bh%8
    const int qt = 31 - (id >> 5);          // big tiles first
    const int b = bh >> 4, h = bh & 15;
    const int tid = threadIdx.x, lane = tid & 63, wave = tid >> 6;
    const int wq = wave >> 1, wk = wave & 1;
    const int l32 = lane & 31, hi = lane >> 5;

    __shared__ alignas(16) __bf16 SMEM[128 * 64 + 64 * 128];  // Ks | Vs (32 KB)
    __bf16* Ks = SMEM;
    __bf16* Vs = SMEM + 128 * 64;

    const size_t base = (size_t)bh * S_LEN * HDIM;   // same for Q, K, Vt
    const int q0 = qt * 64;
    const int q_lane = q0 + wq * 32 + l32;

    bf16x8 qf[4];
#pragma unroll
    for (int j = 0; j < 4; j++)
        qf[j] = *(const bf16x8*)&Q[base + (size_t)q_lane * HDIM + j * 16 + hi * 8];

    bf16x8 onesf;
#pragma unroll
    for (int jj = 0; jj < 8; jj++) onesf[jj] = (__bf16)1.0f;

    f32x16 oacc[2] = {};
    f32x16 lacc = {};

    // staging lane roles
    const int r8k = lane >> 3;
    const int sck = ((lane & 7) ^ r8k) * 8;   // K source chunk (elems)
    const int r4v = lane >> 4;                // V: 4 rows per glds

    const int kb_all = (qt >> 1) + 1;
    const int kl0 = wk * 64;                  // this wave's local k base

    for (int kb = 0; kb < kb_all; kb++) {
        const int k0 = kb * 128;
        __syncthreads();
#pragma unroll
        for (int p = 0; p < 4; p++) {  // K: 128 rows, 8 rows/glds
            const int row = wave * 32 + p * 8;
            __builtin_amdgcn_global_load_lds(
                (const AS1 void*)&K[base + (size_t)(k0 + row + r8k) * HDIM + sck],
                (AS3 void*)&Ks[row * 64], 16, 0, 0);
        }
#pragma unroll
        for (int p = 0; p < 4; p++) {  // V^T: 64 rows x 128 cols, 4 rows/glds
            const int row = wave * 16 + p * 4;
            const int lc = ((lane & 15) ^ ((p * 4 + r4v) & 15)) * 8;
            __builtin_amdgcn_global_load_lds(
                (const AS1 void*)&Vt[base + (size_t)(row + r4v) * S_LEN + k0 + lc],
                (AS3 void*)&Vs[row * 128], 16, 0, 0);
        }
        __syncthreads();

        if (kb == kb_all - 1)
            attn_tile32<true>(Ks, Vs, qf, onesf, oacc, lacc, q_lane, kl0, k0 + kl0, lane);
        else
            attn_tile32<false>(Ks, Vs, qf, onesf, oacc, lacc, q_lane, kl0, k0 + kl0, lane);
    }

    // ---- k-half reduction via LDS scratch (stride 49 f32: conflict-free) ----
    __syncthreads();
    float* scr = (float*)SMEM;
    const int slot = (wq * 64 + lane) * 49;
    if (wk) {
#pragma unroll
        for (int ss = 0; ss < 2; ss++)
#pragma unroll
            for (int r = 0; r < 16; r++) scr[slot + ss * 16 + r] = oacc[ss][r];
#pragma unroll
        for (int r = 0; r < 16; r++) scr[slot + 32 + r] = lacc[r];
    }
    __syncthreads();
    if (!wk) {
#pragma unroll
        for (int ss = 0; ss < 2; ss++)
#pragma unroll
            for (int r = 0; r < 16; r++) oacc[ss][r] += scr[slot + ss * 16 + r];
#pragma unroll
        for (int r = 0; r < 16; r++) lacc[r] += scr[slot + 32 + r];
        float rl[16];
#pragma unroll
        for (int r = 0; r < 16; r++) rl[r] = 1.0f / lacc[r];
#pragma unroll
        for (int ss = 0; ss < 2; ss++)
#pragma unroll
            for (int r = 0; r < 16; r++) {
                const int q = q0 + wq * 32 + (r & 3) + 8 * (r >> 2) + 4 * hi;
                Aout[(size_t)(b * S_LEN + q) * DMODEL + h * 64 + ss * 32 + l32] =
                    (__bf16)(oacc[ss][r] * rl[r]);
            }
    }
}

extern "C" void kernel_launch(void* const* d_in, const int* in_sizes, int n_in,
                              void* d_out, int out_size, void* d_ws, size_t ws_size,
                              hipStream_t stream) {
    const float* x  = (const float*)d_in[0];
    // d_in[1] = mask: causal triu, reproduced analytically
    const float* wq = (const float*)d_in[2];
    const float* bq = (const float*)d_in[3];
    const float* wk = (const float*)d_in[4];
    const float* bk = (const float*)d_in[5];
    const float* wv = (const float*)d_in[6];
    const float* bv = (const float*)d_in[7];
    const float* wo = (const float*)d_in[8];
    const float* bo = (const float*)d_in[9];
    float* out = (float*)d_out;

    char* ws = (char*)d_ws;
    __bf16* xb  = (__bf16*)(ws);                          // 8 MiB
    __bf16* wqT = (__bf16*)(ws + ((size_t)8  << 20));     // 2 MiB each
    __bf16* wkT = (__bf16*)(ws + ((size_t)10 << 20));
    __bf16* wvT = (__bf16*)(ws + ((size_t)12 << 20));
    __bf16* woT = (__bf16*)(ws + ((size_t)14 << 20));
    __bf16* Qb  = (__bf16*)(ws + ((size_t)16 << 20));     // 8 MiB each
    __bf16* Kb  = (__bf16*)(ws + ((size_t)24 << 20));
    __bf16* Vtb = (__bf16*)(ws + ((size_t)32 << 20));     // V^T [B,H,HD,S]
    __bf16* Ab  = (__bf16*)(ws + ((size_t)40 << 20));     // 8 MiB

    cast_x_kernel<<<4096, 256, 0, stream>>>(x, xb);
    transpose_cast_kernel<<<dim3(32, 32, 4), dim3(32, 8), 0, stream>>>(
        wq, wk, wv, wo, wqT, wkT, wvT, woT);
    gemm_qkv_kernel<<<dim3(32, 16, 3), 256, 0, stream>>>(xb, wqT, wkT, wvT, bq, bk, bv, Qb, Kb, Vtb);
    attn_kernel<<<1024, 256, 0, stream>>>(Qb, Kb, Vtb, Ab);
    gemm_out_kernel<<<dim3(64, 16), 256, 0, stream>>>(Ab, woT, bo, out);
}